// Round 1
// baseline (309.400 us; speedup 1.0000x reference)
//
#include <hip/hip_runtime.h>
#include <hip/hip_bf16.h>

#define TB 8
#define TT 4096
#define TC 1024
#define THS 128

typedef __bf16 bf16;
typedef __attribute__((ext_vector_type(8))) __bf16 bf16x8;
typedef __attribute__((ext_vector_type(4))) __bf16 bf16x4;
typedef __attribute__((ext_vector_type(4))) float f32x4;

__device__ __forceinline__ bf16 tobf(float f) {
    unsigned u = __builtin_bit_cast(unsigned, f);
    u += 0x7FFFu + ((u >> 16) & 1u);              // RNE
    unsigned short s = (unsigned short)(u >> 16);
    return __builtin_bit_cast(bf16, s);
}

// ---- W cast+transpose: Wt[w][n][k] = bf16(W_w[k][n]) ----
__global__ __launch_bounds__(256) void wt_kernel(const float* __restrict__ Wq,
                                                 const float* __restrict__ Wk,
                                                 const float* __restrict__ Wv,
                                                 bf16* __restrict__ Wt) {
    int idx = blockIdx.x * 256 + threadIdx.x;     // [3][1024][128] as (w,k,n)
    int n = idx & 127;
    int k = (idx >> 7) & 1023;
    int w = idx >> 17;
    const float* W = (w == 0) ? Wq : (w == 1) ? Wk : Wv;
    Wt[((w << 7) + n) * 1024 + k] = tobf(W[(k << 7) + n]);
}

// ---- fused QKV projection: Q/K/V[b*T+t][d] bf16, q pre-scaled ----
__global__ __launch_bounds__(256) void qkv_kernel(const float* __restrict__ x,
                                                  const bf16* __restrict__ Wt,
                                                  bf16* __restrict__ Q,
                                                  bf16* __restrict__ K,
                                                  bf16* __restrict__ V) {
    __shared__ __align__(16) bf16 xt[64][40];        // 32-col k-tile, stride 40 (80B: 16B-aligned, ~2-way banks)
    __shared__ __align__(16) bf16 wt[3][128][40];
    const int tid = threadIdx.x;
    const int wave = tid >> 6, lane = tid & 63;
    const int g = lane >> 4, lr = lane & 15;
    const long row0 = (long)blockIdx.x * 64;

    f32x4 acc[3][8] = {};

    for (int k0 = 0; k0 < 1024; k0 += 32) {
        __syncthreads();
        #pragma unroll
        for (int i = 0; i < 2; i++) {                // x tile 64x32 f32->bf16
            int r = (tid >> 3) + 32 * i;
            int c4 = (tid & 7) * 4;
            const float4 xv = *reinterpret_cast<const float4*>(&x[(row0 + r) * 1024 + k0 + c4]);
            bf16x4 t;
            t[0] = tobf(xv.x); t[1] = tobf(xv.y); t[2] = tobf(xv.z); t[3] = tobf(xv.w);
            *reinterpret_cast<bf16x4*>(&xt[r][c4]) = t;
        }
        #pragma unroll
        for (int i = 0; i < 6; i++) {                // Wt tiles 3 x 128x32
            int slot = tid + 256 * i;
            int w = slot >> 9;
            int s = slot & 511;
            int n = s >> 2, c8 = (s & 3) * 8;
            *reinterpret_cast<bf16x8*>(&wt[w][n][c8]) =
                *reinterpret_cast<const bf16x8*>(&Wt[((w << 7) + n) * 1024 + k0 + c8]);
        }
        __syncthreads();
        bf16x8 a = *reinterpret_cast<const bf16x8*>(&xt[wave * 16 + lr][g * 8]);
        #pragma unroll
        for (int w = 0; w < 3; w++)
            #pragma unroll
            for (int nt = 0; nt < 8; nt++) {
                bf16x8 bfr = *reinterpret_cast<const bf16x8*>(&wt[w][nt * 16 + lr][g * 8]);
                acc[w][nt] = __builtin_amdgcn_mfma_f32_16x16x32_bf16(a, bfr, acc[w][nt], 0, 0, 0);
            }
    }
    const float qscale = 0.08838834764831845f;       // 128^-0.5
    bf16* outs[3] = {Q, K, V};
    #pragma unroll
    for (int w = 0; w < 3; w++)
        #pragma unroll
        for (int nt = 0; nt < 8; nt++)
            #pragma unroll
            for (int r = 0; r < 4; r++) {
                float v = acc[w][nt][r];
                if (w == 0) v *= qscale;
                long row = row0 + wave * 16 + g * 4 + r;   // C/D: col=lane&15, row=(lane>>4)*4+reg
                outs[w][row * 128 + nt * 16 + lr] = tobf(v);
            }
}

// ---- V transpose: Vt[b][d][t] = V[b][t][d] ----
__global__ __launch_bounds__(256) void vtrans_kernel(const bf16* __restrict__ V,
                                                     bf16* __restrict__ Vt) {
    __shared__ __align__(16) bf16 tile[64][136];
    const int tid = threadIdx.x;
    const int b = blockIdx.y;
    const int t0 = blockIdx.x * 64;
    const long ibase = ((long)b * TT + t0) * 128;
    #pragma unroll
    for (int i = 0; i < 4; i++) {
        int slot = tid + 256 * i;
        int r = slot >> 4, c8 = (slot & 15) * 8;
        *reinterpret_cast<bf16x8*>(&tile[r][c8]) =
            *reinterpret_cast<const bf16x8*>(&V[ibase + r * 128 + c8]);
    }
    __syncthreads();
    #pragma unroll
    for (int i = 0; i < 4; i++) {
        int slot = tid + 256 * i;
        int d = slot >> 3, t8 = (slot & 7) * 8;
        bf16x8 v;
        #pragma unroll
        for (int j = 0; j < 8; j++) v[j] = tile[t8 + j][d];
        *reinterpret_cast<bf16x8*>(&Vt[((long)b * 128 + d) * TT + t0 + t8]) = v;
    }
}

// ---- causal flash attention: out[b][t][d] f32 ----
__global__ __launch_bounds__(256) void attn_kernel(const bf16* __restrict__ Q,
                                                   const bf16* __restrict__ K,
                                                   const bf16* __restrict__ Vt,
                                                   float* __restrict__ out) {
    __shared__ __align__(16) bf16 kt[32][136];   // K tile row-major [kv][d], 272B rows (free banks)
    __shared__ __align__(16) bf16 vt[128][40];   // V^T tile [d][kv]
    __shared__ __align__(16) bf16 pt[4][16][40]; // per-wave P [q][kv]
    const int tid = threadIdx.x;
    const int wave = tid >> 6, lane = tid & 63;
    const int g = lane >> 4, lr = lane & 15;
    const int b = blockIdx.y;
    const int q0 = blockIdx.x * 64;
    const long qbase = (long)b * TT * 128;

    bf16x8 qf[4];                                 // wave's 16 q-rows, A-frag per 32-d chunk
    #pragma unroll
    for (int kc = 0; kc < 4; kc++)
        qf[kc] = *reinterpret_cast<const bf16x8*>(
            &Q[qbase + (long)(q0 + wave * 16 + lr) * 128 + kc * 32 + g * 8]);

    f32x4 o[8] = {};
    float m[4], lsum[4];
    #pragma unroll
    for (int r = 0; r < 4; r++) { m[r] = -__builtin_inff(); lsum[r] = 0.f; }

    const int ntiles = q0 / 32 + 2;
    for (int t = 0; t < ntiles; t++) {
        const int kv0 = t * 32;
        __syncthreads();
        #pragma unroll
        for (int i = 0; i < 2; i++) {             // stage K tile 32x128
            int slot = tid + 256 * i;
            int r = slot >> 4, c8 = (slot & 15) * 8;
            *reinterpret_cast<bf16x8*>(&kt[r][c8]) =
                *reinterpret_cast<const bf16x8*>(&K[qbase + (long)(kv0 + r) * 128 + c8]);
        }
        #pragma unroll
        for (int i = 0; i < 2; i++) {             // stage V^T tile 128x32 (coalesced, vector LDS writes)
            int slot = tid + 256 * i;
            int d = slot >> 2, c8 = (slot & 3) * 8;
            *reinterpret_cast<bf16x8*>(&vt[d][c8]) =
                *reinterpret_cast<const bf16x8*>(&Vt[((long)b * 128 + d) * TT + kv0 + c8]);
        }
        __syncthreads();
        const int qw = q0 + wave * 16;
        if (kv0 > qw + 15) continue;              // fully masked for this wave (barriers stay balanced)

        f32x4 s[2];
        #pragma unroll
        for (int n = 0; n < 2; n++) {             // S = Q K^T  (q pre-scaled)
            f32x4 sa = {0.f, 0.f, 0.f, 0.f};
            #pragma unroll
            for (int kc = 0; kc < 4; kc++) {
                bf16x8 kf = *reinterpret_cast<const bf16x8*>(&kt[n * 16 + lr][kc * 32 + g * 8]);
                sa = __builtin_amdgcn_mfma_f32_16x16x32_bf16(qf[kc], kf, sa, 0, 0, 0);
            }
            s[n] = sa;
        }
        if (kv0 + 31 > qw) {                      // causal mask on diagonal tiles
            #pragma unroll
            for (int n = 0; n < 2; n++)
                #pragma unroll
                for (int r = 0; r < 4; r++) {
                    int qa = qw + g * 4 + r;
                    int kv = kv0 + n * 16 + lr;
                    if (kv > qa) s[n][r] = -__builtin_inff();
                }
        }
        float fr_[4];
        #pragma unroll
        for (int r = 0; r < 4; r++) {             // online softmax, 16-lane butterflies
            float mx = fmaxf(s[0][r], s[1][r]);
            #pragma unroll
            for (int off = 1; off < 16; off <<= 1)
                mx = fmaxf(mx, __shfl_xor(mx, off, 64));
            float mn = fmaxf(m[r], mx);
            float p0 = __expf(s[0][r] - mn);
            float p1 = __expf(s[1][r] - mn);
            float rs = p0 + p1;
            #pragma unroll
            for (int off = 1; off < 16; off <<= 1)
                rs += __shfl_xor(rs, off, 64);
            float fr = __expf(m[r] - mn);
            lsum[r] = lsum[r] * fr + rs;
            m[r] = mn;
            fr_[r] = fr;
            pt[wave][g * 4 + r][lr] = tobf(p0);   // P into A-frag layout
            pt[wave][g * 4 + r][16 + lr] = tobf(p1);
        }
        #pragma unroll
        for (int dt = 0; dt < 8; dt++)
            #pragma unroll
            for (int r = 0; r < 4; r++)
                o[dt][r] *= fr_[r];
        asm volatile("s_waitcnt lgkmcnt(0)" ::: "memory");   // P writes visible to whole wave
        bf16x8 pf = *reinterpret_cast<const bf16x8*>(&pt[wave][lr][g * 8]);
        #pragma unroll
        for (int dt = 0; dt < 8; dt++) {          // O += P V
            bf16x8 vf = *reinterpret_cast<const bf16x8*>(&vt[dt * 16 + lr][g * 8]);
            o[dt] = __builtin_amdgcn_mfma_f32_16x16x32_bf16(pf, vf, o[dt], 0, 0, 0);
        }
    }
    #pragma unroll
    for (int dt = 0; dt < 8; dt++)
        #pragma unroll
        for (int r = 0; r < 4; r++) {
            long row = q0 + wave * 16 + g * 4 + r;
            out[qbase + row * 128 + dt * 16 + lr] = o[dt][r] / lsum[r];
        }
}

extern "C" void kernel_launch(void* const* d_in, const int* in_sizes, int n_in,
                              void* d_out, int out_size, void* d_ws, size_t ws_size,
                              hipStream_t stream) {
    const float* x  = (const float*)d_in[0];
    const float* Wq = (const float*)d_in[1];
    const float* Wk = (const float*)d_in[2];
    const float* Wv = (const float*)d_in[3];
    float* out = (float*)d_out;
    bf16* Q  = (bf16*)d_ws;                       // [32768][128]
    bf16* K  = Q  + (size_t)32768 * 128;
    bf16* V  = K  + (size_t)32768 * 128;
    bf16* Wt = V  + (size_t)32768 * 128;          // [3][128][1024]
    bf16* Vt = Wt + (size_t)3 * 128 * 1024;       // [8][128][4096]
    wt_kernel<<<1536, 256, 0, stream>>>(Wq, Wk, Wv, Wt);
    qkv_kernel<<<512, 256, 0, stream>>>(x, Wt, Q, K, V);
    vtrans_kernel<<<dim3(64, 8), 256, 0, stream>>>(V, Vt);
    attn_kernel<<<dim3(64, 8), 256, 0, stream>>>(Q, K, Vt, out);
}

// Round 2
// 204.022 us; speedup vs baseline: 1.5165x; 1.5165x over previous
//
#include <hip/hip_runtime.h>
#include <hip/hip_bf16.h>

#define TB 8
#define TT 4096
#define TC 1024
#define THS 128

typedef __bf16 bf16;
typedef __attribute__((ext_vector_type(8))) __bf16 bf16x8;
typedef __attribute__((ext_vector_type(4))) __bf16 bf16x4;
typedef __attribute__((ext_vector_type(4))) float f32x4;

__device__ __forceinline__ bf16 tobf(float f) {
    unsigned u = __builtin_bit_cast(unsigned, f);
    u += 0x7FFFu + ((u >> 16) & 1u);              // RNE
    unsigned short s = (unsigned short)(u >> 16);
    return __builtin_bit_cast(bf16, s);
}

// ---- W cast+transpose: Wt[w][n][k] = bf16(W_w[k][n]) ----
__global__ __launch_bounds__(256) void wt_kernel(const float* __restrict__ Wq,
                                                 const float* __restrict__ Wk,
                                                 const float* __restrict__ Wv,
                                                 bf16* __restrict__ Wt) {
    int idx = blockIdx.x * 256 + threadIdx.x;     // [3][1024][128] as (w,k,n)
    int n = idx & 127;
    int k = (idx >> 7) & 1023;
    int w = idx >> 17;
    const float* W = (w == 0) ? Wq : (w == 1) ? Wk : Wv;
    Wt[((w << 7) + n) * 1024 + k] = tobf(W[(k << 7) + n]);
}

// ---- fused QKV projection: Q/K/V[b*T+t][d] bf16, q pre-scaled ----
__global__ __launch_bounds__(256) void qkv_kernel(const float* __restrict__ x,
                                                  const bf16* __restrict__ Wt,
                                                  bf16* __restrict__ Q,
                                                  bf16* __restrict__ K,
                                                  bf16* __restrict__ V) {
    __shared__ __align__(16) bf16 xt[64][40];
    __shared__ __align__(16) bf16 wt[3][128][40];
    const int tid = threadIdx.x;
    const int wave = tid >> 6, lane = tid & 63;
    const int g = lane >> 4, lr = lane & 15;
    const long row0 = (long)blockIdx.x * 64;

    f32x4 acc[3][8] = {};

    for (int k0 = 0; k0 < 1024; k0 += 32) {
        __syncthreads();
        #pragma unroll
        for (int i = 0; i < 2; i++) {                // x tile 64x32 f32->bf16
            int r = (tid >> 3) + 32 * i;
            int c4 = (tid & 7) * 4;
            const float4 xv = *reinterpret_cast<const float4*>(&x[(row0 + r) * 1024 + k0 + c4]);
            bf16x4 t;
            t[0] = tobf(xv.x); t[1] = tobf(xv.y); t[2] = tobf(xv.z); t[3] = tobf(xv.w);
            *reinterpret_cast<bf16x4*>(&xt[r][c4]) = t;
        }
        #pragma unroll
        for (int i = 0; i < 6; i++) {                // Wt tiles 3 x 128x32
            int slot = tid + 256 * i;
            int w = slot >> 9;
            int s = slot & 511;
            int n = s >> 2, c8 = (s & 3) * 8;
            *reinterpret_cast<bf16x8*>(&wt[w][n][c8]) =
                *reinterpret_cast<const bf16x8*>(&Wt[((w << 7) + n) * 1024 + k0 + c8]);
        }
        __syncthreads();
        bf16x8 a = *reinterpret_cast<const bf16x8*>(&xt[wave * 16 + lr][g * 8]);
        #pragma unroll
        for (int w = 0; w < 3; w++)
            #pragma unroll
            for (int nt = 0; nt < 8; nt++) {
                bf16x8 bfr = *reinterpret_cast<const bf16x8*>(&wt[w][nt * 16 + lr][g * 8]);
                acc[w][nt] = __builtin_amdgcn_mfma_f32_16x16x32_bf16(a, bfr, acc[w][nt], 0, 0, 0);
            }
    }
    const float qscale = 0.08838834764831845f;       // 128^-0.5
    bf16* outs[3] = {Q, K, V};
    #pragma unroll
    for (int w = 0; w < 3; w++)
        #pragma unroll
        for (int nt = 0; nt < 8; nt++)
            #pragma unroll
            for (int r = 0; r < 4; r++) {
                float v = acc[w][nt][r];
                if (w == 0) v *= qscale;
                long row = row0 + wave * 16 + g * 4 + r;   // C/D: col=lane&15, row=(lane>>4)*4+reg
                outs[w][row * 128 + nt * 16 + lr] = tobf(v);
            }
}

// ---- V transpose: Vt[b][d][t] = V[b][t][d] ----
__global__ __launch_bounds__(256) void vtrans_kernel(const bf16* __restrict__ V,
                                                     bf16* __restrict__ Vt) {
    __shared__ __align__(16) bf16 tile[64][136];
    const int tid = threadIdx.x;
    const int b = blockIdx.y;
    const int t0 = blockIdx.x * 64;
    const long ibase = ((long)b * TT + t0) * 128;
    #pragma unroll
    for (int i = 0; i < 4; i++) {
        int slot = tid + 256 * i;
        int r = slot >> 4, c8 = (slot & 15) * 8;
        *reinterpret_cast<bf16x8*>(&tile[r][c8]) =
            *reinterpret_cast<const bf16x8*>(&V[ibase + r * 128 + c8]);
    }
    __syncthreads();
    #pragma unroll
    for (int i = 0; i < 4; i++) {
        int slot = tid + 256 * i;
        int d = slot >> 3, t8 = (slot & 7) * 8;
        bf16x8 v;
        #pragma unroll
        for (int j = 0; j < 8; j++) v[j] = tile[t8 + j][d];
        *reinterpret_cast<bf16x8*>(&Vt[((long)b * 128 + d) * TT + t0 + t8]) = v;
    }
}

// ---- causal flash attention, work-balanced pair blocks ----
// Block = (pair, batch): processes q-tile `pair` then q-tile `63-pair` (64 rows each),
// so every block does exactly 65 KV-tiles of KBLK=64. Grid linear = pair*8 + b so the
// XCD round-robin heuristic gives each XCD one batch (K/V L2-resident).
__global__ __launch_bounds__(256) void attn_kernel(const bf16* __restrict__ Q,
                                                   const bf16* __restrict__ K,
                                                   const bf16* __restrict__ Vt,
                                                   float* __restrict__ out) {
    __shared__ __align__(16) bf16 kt[2][64][136];   // K tile [kv][d], dbuf
    __shared__ __align__(16) bf16 vt[2][128][72];   // V^T tile [d][kv], dbuf
    __shared__ __align__(16) bf16 pt[4][16][72];    // per-wave P [q][kv]
    const int tid = threadIdx.x;
    const int wave = tid >> 6, lane = tid & 63;
    const int g = lane >> 4, lr = lane & 15;
    const int pair = blockIdx.x >> 3;
    const int b = blockIdx.x & 7;
    const long qbase = (long)b * TT * 128;
    const long vbase = (long)b * 128 * TT;

    bf16x8 rk[4], rv[4];                             // staging regs (async-split)

    #pragma unroll 1
    for (int phase = 0; phase < 2; phase++) {
        const int qt = (phase == 0) ? pair : 63 - pair;
        const int q0 = qt * 64;
        const int qw = q0 + wave * 16;
        const int nt = qt + 1;

        bf16x8 qf[4];
        #pragma unroll
        for (int kc = 0; kc < 4; kc++)
            qf[kc] = *reinterpret_cast<const bf16x8*>(
                &Q[qbase + (long)(q0 + wave * 16 + lr) * 128 + kc * 32 + g * 8]);

        f32x4 o[8] = {};
        float m[4], lsum[4];
        #pragma unroll
        for (int r = 0; r < 4; r++) { m[r] = -__builtin_inff(); lsum[r] = 0.f; }

        // prologue: issue tile-0 loads
        #pragma unroll
        for (int i = 0; i < 4; i++) {
            int slot = tid + 256 * i;
            rk[i] = *reinterpret_cast<const bf16x8*>(
                &K[qbase + (long)(slot >> 4) * 128 + (slot & 15) * 8]);
            rv[i] = *reinterpret_cast<const bf16x8*>(
                &Vt[vbase + (long)(slot >> 3) * TT + (slot & 7) * 8]);
        }

        #pragma unroll 1
        for (int t = 0; t < nt; t++) {
            const int kv0 = t * 64;
            const int cur = t & 1;
            #pragma unroll
            for (int i = 0; i < 4; i++) {            // commit tile t to LDS
                int slot = tid + 256 * i;
                *reinterpret_cast<bf16x8*>(&kt[cur][slot >> 4][(slot & 15) * 8]) = rk[i];
                *reinterpret_cast<bf16x8*>(&vt[cur][slot >> 3][(slot & 7) * 8]) = rv[i];
            }
            if (t + 1 < nt) {                        // issue tile t+1 (overlaps compute)
                const int kn = kv0 + 64;
                #pragma unroll
                for (int i = 0; i < 4; i++) {
                    int slot = tid + 256 * i;
                    rk[i] = *reinterpret_cast<const bf16x8*>(
                        &K[qbase + (long)(kn + (slot >> 4)) * 128 + (slot & 15) * 8]);
                    rv[i] = *reinterpret_cast<const bf16x8*>(
                        &Vt[vbase + (long)(slot >> 3) * TT + kn + (slot & 7) * 8]);
                }
            }
            __syncthreads();                         // tile t visible; prev buffer free

            f32x4 s[4];
            #pragma unroll
            for (int n = 0; n < 4; n++) {            // S = Q K^T, skip n-tiles past diagonal
                if (kv0 + n * 16 <= qw + 15) {
                    f32x4 sa = {0.f, 0.f, 0.f, 0.f};
                    #pragma unroll
                    for (int kc = 0; kc < 4; kc++) {
                        bf16x8 kf = *reinterpret_cast<const bf16x8*>(
                            &kt[cur][n * 16 + lr][kc * 32 + g * 8]);
                        sa = __builtin_amdgcn_mfma_f32_16x16x32_bf16(qf[kc], kf, sa, 0, 0, 0);
                    }
                    s[n] = sa;
                } else {
                    s[n] = f32x4{-__builtin_inff(), -__builtin_inff(),
                                 -__builtin_inff(), -__builtin_inff()};
                }
            }
            if (t == nt - 1) {                       // causal mask on the diagonal tile
                #pragma unroll
                for (int n = 0; n < 4; n++)
                    #pragma unroll
                    for (int r = 0; r < 4; r++)
                        if (kv0 + n * 16 + lr > qw + g * 4 + r) s[n][r] = -__builtin_inff();
            }
            float fr_[4];
            #pragma unroll
            for (int r = 0; r < 4; r++) {            // online softmax, 16-lane butterflies
                float mx = fmaxf(fmaxf(s[0][r], s[1][r]), fmaxf(s[2][r], s[3][r]));
                #pragma unroll
                for (int off = 1; off < 16; off <<= 1)
                    mx = fmaxf(mx, __shfl_xor(mx, off, 64));
                float mn = fmaxf(m[r], mx);
                float p0 = __expf(s[0][r] - mn);
                float p1 = __expf(s[1][r] - mn);
                float p2 = __expf(s[2][r] - mn);
                float p3 = __expf(s[3][r] - mn);
                float rs = (p0 + p1) + (p2 + p3);
                #pragma unroll
                for (int off = 1; off < 16; off <<= 1)
                    rs += __shfl_xor(rs, off, 64);
                float fr = __expf(m[r] - mn);
                lsum[r] = lsum[r] * fr + rs;
                m[r] = mn;
                fr_[r] = fr;
                pt[wave][g * 4 + r][lr]      = tobf(p0);
                pt[wave][g * 4 + r][16 + lr] = tobf(p1);
                pt[wave][g * 4 + r][32 + lr] = tobf(p2);
                pt[wave][g * 4 + r][48 + lr] = tobf(p3);
            }
            #pragma unroll
            for (int dt = 0; dt < 8; dt++)
                #pragma unroll
                for (int r = 0; r < 4; r++)
                    o[dt][r] *= fr_[r];
            asm volatile("s_waitcnt lgkmcnt(0)" ::: "memory");   // P writes visible (wave-local)
            bf16x8 pf0 = *reinterpret_cast<const bf16x8*>(&pt[wave][lr][g * 8]);
            bf16x8 pf1 = *reinterpret_cast<const bf16x8*>(&pt[wave][lr][32 + g * 8]);
            #pragma unroll
            for (int dt = 0; dt < 8; dt++) {         // O += P V
                bf16x8 vf0 = *reinterpret_cast<const bf16x8*>(&vt[cur][dt * 16 + lr][g * 8]);
                o[dt] = __builtin_amdgcn_mfma_f32_16x16x32_bf16(pf0, vf0, o[dt], 0, 0, 0);
                bf16x8 vf1 = *reinterpret_cast<const bf16x8*>(&vt[cur][dt * 16 + lr][32 + g * 8]);
                o[dt] = __builtin_amdgcn_mfma_f32_16x16x32_bf16(pf1, vf1, o[dt], 0, 0, 0);
            }
        }
        #pragma unroll
        for (int r = 0; r < 4; r++) {
            float il = 1.0f / lsum[r];
            #pragma unroll
            for (int dt = 0; dt < 8; dt++) {
                long row = q0 + wave * 16 + g * 4 + r;
                out[qbase + row * 128 + dt * 16 + lr] = o[dt][r] * il;
            }
        }
        __syncthreads();                             // LDS safe for next phase
    }
}

extern "C" void kernel_launch(void* const* d_in, const int* in_sizes, int n_in,
                              void* d_out, int out_size, void* d_ws, size_t ws_size,
                              hipStream_t stream) {
    const float* x  = (const float*)d_in[0];
    const float* Wq = (const float*)d_in[1];
    const float* Wk = (const float*)d_in[2];
    const float* Wv = (const float*)d_in[3];
    float* out = (float*)d_out;
    bf16* Q  = (bf16*)d_ws;                       // [32768][128]
    bf16* K  = Q  + (size_t)32768 * 128;
    bf16* V  = K  + (size_t)32768 * 128;
    bf16* Wt = V  + (size_t)32768 * 128;          // [3][128][1024]
    bf16* Vt = Wt + (size_t)3 * 128 * 1024;       // [8][128][4096]
    wt_kernel<<<1536, 256, 0, stream>>>(Wq, Wk, Wv, Wt);
    qkv_kernel<<<512, 256, 0, stream>>>(x, Wt, Q, K, V);
    vtrans_kernel<<<dim3(64, 8), 256, 0, stream>>>(V, Vt);
    attn_kernel<<<256, 256, 0, stream>>>(Q, K, Vt, out);
}